// Round 14
// baseline (111.650 us; speedup 1.0000x reference)
//
#include <hip/hip_runtime.h>

// Problem constants (fixed by setup_inputs).
constexpr int L  = 512;   // sequence length
constexpr int CS = 384;   // c_s
constexpr int CH = 32;    // c_h
constexpr int CZ = 128;   // c_z
constexpr float LN_EPS = 1e-5f;

typedef float f2 __attribute__((ext_vector_type(2)));
typedef float f4 __attribute__((ext_vector_type(4)));

// ---------------------------------------------------------------------------
// Kernel 1 (v2): LayerNorm + dual projection + mask.  (R11-exact)
// ---------------------------------------------------------------------------
__global__ __launch_bounds__(64) void k_ln_proj(
    const float* __restrict__ s, const int* __restrict__ mask,
    const float* __restrict__ ln_scale, const float* __restrict__ ln_bias,
    const float* __restrict__ w1, const float* __restrict__ b1,
    const float* __restrict__ w2, const float* __restrict__ b2,
    float* __restrict__ a, float* __restrict__ b)
{
    __shared__ float sn_lds[CS];
    const int lane = threadIdx.x;
    const int row  = blockIdx.x;

    const float* srow = s + row * CS;
    float v[6];
    float sum = 0.f, sumsq = 0.f;
#pragma unroll
    for (int q = 0; q < 6; ++q) {
        v[q] = srow[lane + 64 * q];
        sum   += v[q];
        sumsq += v[q] * v[q];
    }
#pragma unroll
    for (int off = 32; off; off >>= 1) {
        sum   += __shfl_xor(sum, off);
        sumsq += __shfl_xor(sumsq, off);
    }
    const float mu   = sum * (1.f / CS);
    const float var  = sumsq * (1.f / CS) - mu * mu;
    const float rstd = rsqrtf(var + LN_EPS);
#pragma unroll
    for (int q = 0; q < 6; ++q) {
        const int k = lane + 64 * q;
        sn_lds[k] = (v[q] - mu) * rstd * ln_scale[k] + ln_bias[k];
    }
    __syncthreads();

    const int c    = lane & 31;
    const int half = lane >> 5;
    const float* W  = half ? w2 : w1;
    const float* Bv = half ? b2 : b1;
    float acc = 0.f;
#pragma unroll 4
    for (int k = 0; k < CS; ++k)
        acc += sn_lds[k] * W[k * CH + c];
    const float m = (float)mask[row];
    const float outv = (acc + Bv[c]) * m;
    (half ? b : a)[row * CH + c] = outv;
}

// ---------------------------------------------------------------------------
// Kernel 2 (v2): T[j][c][z] = sum_e b[j][e] * w_out[...].  (R11-exact)
// ---------------------------------------------------------------------------
__global__ __launch_bounds__(512) void k_T(
    const float* __restrict__ b, const float* __restrict__ w_out,
    float* __restrict__ T)
{
    const int j0  = blockIdx.x * 2;
    const int t   = threadIdx.x;
    const int c   = t >> 4;            // 0..31
    const int zo  = t & 15;            // z-octet: z = 8*zo .. 8*zo+7

    float bj0[CH], bj1[CH];
#pragma unroll
    for (int e = 0; e < CH; ++e) {
        bj0[e] = b[j0 * CH + e];       // wave-uniform -> broadcast
        bj1[e] = b[(j0 + 1) * CH + e];
    }

    const float* wbase = w_out + (size_t)(c * CH) * CZ + 8 * zo;
    f4 a00 = 0.f, a01 = 0.f, a10 = 0.f, a11 = 0.f;
#pragma unroll
    for (int e = 0; e < CH; ++e) {
        const f4 w0 = *(const f4*)(wbase + e * CZ);
        const f4 w1 = *(const f4*)(wbase + e * CZ + 4);
        a00 += bj0[e] * w0;  a01 += bj0[e] * w1;
        a10 += bj1[e] * w0;  a11 += bj1[e] * w1;
    }

    float* Tp0 = T + (size_t)j0 * (CH * CZ) + c * CZ + 8 * zo;
    *(f4*)(Tp0)     = a00;
    *(f4*)(Tp0 + 4) = a01;
    float* Tp1 = Tp0 + CH * CZ;
    *(f4*)(Tp1)     = a10;
    *(f4*)(Tp1 + 4) = a11;
}

// ---------------------------------------------------------------------------
// Kernel 3 (pass A): compute z and write to ws2 in BLOCK-LINEAR layout
//   ws2[bid][ii][jl][z]  (bid: j0=(bid&63)*8, i0=(bid>>6)*64)
// Each block sweeps its own 256 KB region linearly at 4 KB/step — the exact
// pattern R13's prefill proved runs at ~7 TB/s (vs 1.8 TB/s for the 8 KB @
// 256 KB-stride pattern every single-pass layout is forced into by the
// T-in-VGPR register economics). Plain stores: L2/L3-buffered, and ws2
// (134 MB) stays Infinity-Cache-resident for pass B. Compute is R11-exact.
// ---------------------------------------------------------------------------
__global__ __launch_bounds__(512) void k_mainA(
    const float* __restrict__ a, const float* __restrict__ T,
    const float* __restrict__ b_out, float* __restrict__ ws2)
{
    __shared__ float a_lds[64][CH];    // 8 KB

    const int bid = blockIdx.x;
    const int j0  = (bid & 63) * 8;
    const int i0  = (bid >> 6) * 64;
    const int t   = threadIdx.x;
    const int wave = t >> 6;
    const int lane = t & 63;
    const int j    = j0 + wave;

    // Stage a-tile: 2048 floats, 512 threads x float4.
    ((float4*)a_lds)[t] = ((const float4*)(a + (size_t)i0 * CH))[t];

    // T[j] column pair for this lane: 64 VGPRs.
    float2 T_reg[CH];
    const float* Tj = T + (size_t)j * (CH * CZ) + 2 * lane;
#pragma unroll
    for (int c = 0; c < CH; ++c)
        T_reg[c] = *(const float2*)(Tj + c * CZ);

    const float2 bo = *(const float2*)&b_out[2 * lane];
    // Block-linear destination: region of 64 KB floats (256 KB bytes).
    float* wp = ws2 + (size_t)bid * (64 * 1024) + wave * 128 + 2 * lane;

    __syncthreads();

#pragma unroll 2
    for (int ii = 0; ii < 64; ++ii) {
        const float4* ap = (const float4*)&a_lds[ii][0];
        float av[CH];
#pragma unroll
        for (int q = 0; q < 8; ++q) {
            const float4 tmp = ap[q];
            av[4 * q + 0] = tmp.x;
            av[4 * q + 1] = tmp.y;
            av[4 * q + 2] = tmp.z;
            av[4 * q + 3] = tmp.w;
        }
        float ax = 0.f, ay = 0.f;
#pragma unroll
        for (int c = 0; c < CH; ++c) {
            ax += av[c] * T_reg[c].x;
            ay += av[c] * T_reg[c].y;
        }
        f2 o;
        o.x = ax + bo.x;
        o.y = ay + bo.y;
        *(f2*)(wp + ii * 1024) = o;    // linear 4 KB/block-step
    }
}

// ---------------------------------------------------------------------------
// Kernel 4 (pass B): permutation copy ws2 -> out.
// Layout algebra: ws2[(ib*64+jb)*65536 + ii*1024 + u]  (u = jl*128 + z)
//   maps to      out[(ib*64+ii)*65536 + jb*1024 + u]   — 1024-float runs
// copy verbatim. Block = one i: WRITES sweep out[i] (256 KB) linearly at
// 8 KB/iter; READS are 4 KB chunks at 256 KB stride served by the L3
// (ws2 just written, 134 MB < 256 MB IC). 512 thr, f4, 2 jb per iter.
// ---------------------------------------------------------------------------
__global__ __launch_bounds__(512) void k_perm(
    const float* __restrict__ ws2, float* __restrict__ out)
{
    const int i  = blockIdx.x;
    const int ib = i >> 6;
    const int ii = i & 63;
    const int t  = threadIdx.x;
    const int jh = t >> 8;             // 0..1: which jb of the pair
    const int u4 = (t & 255) * 4;      // float offset within 1024-run

    const float* src = ws2 + (size_t)(ib * 64 + jh) * 65536 + ii * 1024 + u4;
    float*       dst = out + (size_t)i * 65536 + jh * 1024 + u4;

#pragma unroll 4
    for (int k = 0; k < 32; ++k) {
        const f4 v = *(const f4*)(src + (size_t)k * 2 * 65536);
        *(f4*)(dst + k * 2048) = v;
    }
}

// ---------------------------------------------------------------------------
extern "C" void kernel_launch(void* const* d_in, const int* in_sizes, int n_in,
                              void* d_out, int out_size, void* d_ws, size_t ws_size,
                              hipStream_t stream) {
    const float* s        = (const float*)d_in[0];
    const int*   mask     = (const int*)d_in[1];
    const float* ln_scale = (const float*)d_in[2];
    const float* ln_bias  = (const float*)d_in[3];
    const float* w1       = (const float*)d_in[4];
    const float* b1       = (const float*)d_in[5];
    const float* w2       = (const float*)d_in[6];
    const float* b2       = (const float*)d_in[7];
    const float* w_out    = (const float*)d_in[8];
    const float* b_out    = (const float*)d_in[9];
    float* out = (float*)d_out;

    // Workspace: a [16K], b [16K], T [2M floats = 8 MB], ws2 [33.5M = 134 MB].
    float* a   = (float*)d_ws;
    float* b   = a + L * CH;
    float* T   = b + L * CH;
    float* ws2 = T + (size_t)L * CH * CZ;

    k_ln_proj<<<L, 64, 0, stream>>>(s, mask, ln_scale, ln_bias,
                                    w1, b1, w2, b2, a, b);
    k_T<<<L / 2, 512, 0, stream>>>(b, w_out, T);
    k_mainA<<<512, 512, 0, stream>>>(a, T, b_out, ws2);
    k_perm<<<L, 512, 0, stream>>>(ws2, out);
}

// Round 15
// 74.793 us; speedup vs baseline: 1.4928x; 1.4928x over previous
//
#include <hip/hip_runtime.h>

// Problem constants (fixed by setup_inputs).
constexpr int L  = 512;   // sequence length
constexpr int CS = 384;   // c_s
constexpr int CH = 32;    // c_h
constexpr int CZ = 128;   // c_z
constexpr float LN_EPS = 1e-5f;

typedef float f2 __attribute__((ext_vector_type(2)));
typedef float f4 __attribute__((ext_vector_type(4)));

// ---------------------------------------------------------------------------
// Kernel 1 (v2): LayerNorm + dual projection + mask.  (R11-exact)
// ---------------------------------------------------------------------------
__global__ __launch_bounds__(64) void k_ln_proj(
    const float* __restrict__ s, const int* __restrict__ mask,
    const float* __restrict__ ln_scale, const float* __restrict__ ln_bias,
    const float* __restrict__ w1, const float* __restrict__ b1,
    const float* __restrict__ w2, const float* __restrict__ b2,
    float* __restrict__ a, float* __restrict__ b)
{
    __shared__ float sn_lds[CS];
    const int lane = threadIdx.x;
    const int row  = blockIdx.x;

    const float* srow = s + row * CS;
    float v[6];
    float sum = 0.f, sumsq = 0.f;
#pragma unroll
    for (int q = 0; q < 6; ++q) {
        v[q] = srow[lane + 64 * q];
        sum   += v[q];
        sumsq += v[q] * v[q];
    }
#pragma unroll
    for (int off = 32; off; off >>= 1) {
        sum   += __shfl_xor(sum, off);
        sumsq += __shfl_xor(sumsq, off);
    }
    const float mu   = sum * (1.f / CS);
    const float var  = sumsq * (1.f / CS) - mu * mu;
    const float rstd = rsqrtf(var + LN_EPS);
#pragma unroll
    for (int q = 0; q < 6; ++q) {
        const int k = lane + 64 * q;
        sn_lds[k] = (v[q] - mu) * rstd * ln_scale[k] + ln_bias[k];
    }
    __syncthreads();

    const int c    = lane & 31;
    const int half = lane >> 5;
    const float* W  = half ? w2 : w1;
    const float* Bv = half ? b2 : b1;
    float acc = 0.f;
#pragma unroll 4
    for (int k = 0; k < CS; ++k)
        acc += sn_lds[k] * W[k * CH + c];
    const float m = (float)mask[row];
    const float outv = (acc + Bv[c]) * m;
    (half ? b : a)[row * CH + c] = outv;
}

// ---------------------------------------------------------------------------
// Kernel 2 (NEW): G[i][e][z] = sum_c a[i][c] * w_out[(c*CH+e)*CZ + z].
// (8 MB in ws — replaces k_T; it's k_T with a<->b roles so that the MAIN
// kernel can be i-stationary and write out[i] LINEARLY.)
// grid = 256 blocks; block owns an i-PAIR; thread owns (e, z-octet).
// w_out L2 demand = 256 x 512 KB = 134 MB (~4 us at L2 BW); stores linear.
// ---------------------------------------------------------------------------
__global__ __launch_bounds__(512) void k_G(
    const float* __restrict__ a, const float* __restrict__ w_out,
    float* __restrict__ G)
{
    const int i0 = blockIdx.x * 2;
    const int t  = threadIdx.x;
    const int e  = t >> 4;             // 0..31
    const int zo = t & 15;             // z-octet: z = 8*zo .. 8*zo+7

    float a0[CH], a1[CH];
#pragma unroll
    for (int c = 0; c < CH; ++c) {
        a0[c] = a[i0 * CH + c];        // wave-uniform -> broadcast
        a1[c] = a[(i0 + 1) * CH + c];
    }

    const float* wbase = w_out + (size_t)e * CZ + 8 * zo;   // + c*CH*CZ per c
    f4 g00 = 0.f, g01 = 0.f, g10 = 0.f, g11 = 0.f;
#pragma unroll
    for (int c = 0; c < CH; ++c) {
        const f4 w0 = *(const f4*)(wbase + (size_t)c * (CH * CZ));
        const f4 w1 = *(const f4*)(wbase + (size_t)c * (CH * CZ) + 4);
        g00 += a0[c] * w0;  g01 += a0[c] * w1;
        g10 += a1[c] * w0;  g11 += a1[c] * w1;
    }

    float* Gp0 = G + (size_t)i0 * (CH * CZ) + e * CZ + 8 * zo;
    *(f4*)(Gp0)     = g00;
    *(f4*)(Gp0 + 4) = g01;
    float* Gp1 = Gp0 + CH * CZ;
    *(f4*)(Gp1)     = g10;
    *(f4*)(Gp1 + 4) = g11;
}

// ---------------------------------------------------------------------------
// Kernel 3 (v4): z[i,j,:] = sum_e b[j,e] * G[i,e,:] + b_out.
// BLOCK = ONE OUTPUT ROW i  ->  out[i] is 256 KB CONTIGUOUS and the block
// sweeps it linearly at 4 KB/step (j = 8*s + wave) — the exact pattern R13's
// prefill proved runs at ~7 TB/s, vs ~1.8 TB/s for every <=8KB@256KB-stride
// pattern (R3-R11 write-side, R14 pass-B read-side). The corner-turn now
// happens in registers (G i-stationary), not in DRAM.
// Lane holds G[i] column-pair in 64 VGPRs (R11 economics); b fully staged in
// LDS (64 KB); per step: 8 uniform b128 broadcast reads of b[j] + 64 FMA +
// one plain f2 store. Instruction mix identical to R14 pass A.
// grid = 512, block = 512 (2 blocks/CU; launch_bounds caps VGPR at 128).
// ---------------------------------------------------------------------------
__global__ __launch_bounds__(512, 4) void k_main(
    const float* __restrict__ b, const float* __restrict__ G,
    const float* __restrict__ b_out, float* __restrict__ out)
{
    __shared__ float b_lds[L][CH];     // 64 KB: entire b matrix

    const int i    = blockIdx.x;
    const int t    = threadIdx.x;
    const int wave = t >> 6;
    const int lane = t & 63;

    // Stage all of b: 16384 floats = 512 threads x 8 float4.
#pragma unroll
    for (int k = 0; k < 8; ++k)
        ((f4*)b_lds)[t + k * 512] = ((const f4*)b)[t + k * 512];

    // G[i] column pair for this lane: 64 VGPRs (coalesced 512 B loads,
    // G is L3/L2-hot from k_G).
    f2 G_reg[CH];
    const float* Gi = G + (size_t)i * (CH * CZ) + 2 * lane;
#pragma unroll
    for (int e = 0; e < CH; ++e)
        G_reg[e] = *(const f2*)(Gi + e * CZ);

    const f2 bo = *(const f2*)&b_out[2 * lane];
    float* op = out + (size_t)i * (L * CZ) + 2 * lane;

    __syncthreads();

#pragma unroll 2
    for (int s = 0; s < 64; ++s) {
        const int j = s * 8 + wave;
        const f4* bp = (const f4*)&b_lds[j][0];
        float bv[CH];
#pragma unroll
        for (int q = 0; q < 8; ++q) {
            const f4 tmp = bp[q];
            bv[4 * q + 0] = tmp.x;
            bv[4 * q + 1] = tmp.y;
            bv[4 * q + 2] = tmp.z;
            bv[4 * q + 3] = tmp.w;
        }
        float ax = 0.f, ay = 0.f;
#pragma unroll
        for (int e = 0; e < CH; ++e) {
            ax += bv[e] * G_reg[e].x;
            ay += bv[e] * G_reg[e].y;
        }
        f2 o;
        o.x = ax + bo.x;
        o.y = ay + bo.y;
        *(f2*)(op + j * CZ) = o;       // block-linear: 4 KB per block-step
    }
}

// ---------------------------------------------------------------------------
extern "C" void kernel_launch(void* const* d_in, const int* in_sizes, int n_in,
                              void* d_out, int out_size, void* d_ws, size_t ws_size,
                              hipStream_t stream) {
    const float* s        = (const float*)d_in[0];
    const int*   mask     = (const int*)d_in[1];
    const float* ln_scale = (const float*)d_in[2];
    const float* ln_bias  = (const float*)d_in[3];
    const float* w1       = (const float*)d_in[4];
    const float* b1       = (const float*)d_in[5];
    const float* w2       = (const float*)d_in[6];
    const float* b2       = (const float*)d_in[7];
    const float* w_out    = (const float*)d_in[8];
    const float* b_out    = (const float*)d_in[9];
    float* out = (float*)d_out;

    // Workspace: a [512*32], b [512*32], G [512*32*128]  (8.125 MB total).
    float* a = (float*)d_ws;
    float* b = a + L * CH;
    float* G = b + L * CH;

    k_ln_proj<<<L, 64, 0, stream>>>(s, mask, ln_scale, ln_bias,
                                    w1, b1, w2, b2, a, b);
    k_G<<<L / 2, 512, 0, stream>>>(a, w_out, G);
    k_main<<<L, 512, 0, stream>>>(b, G, b_out, out);
}

// Round 16
// 72.377 us; speedup vs baseline: 1.5426x; 1.0334x over previous
//
#include <hip/hip_runtime.h>

// Problem constants (fixed by setup_inputs).
constexpr int L  = 512;   // sequence length
constexpr int CS = 384;   // c_s
constexpr int CH = 32;    // c_h
constexpr int CZ = 128;   // c_z
constexpr float LN_EPS = 1e-5f;

typedef float f2 __attribute__((ext_vector_type(2)));
typedef float f4 __attribute__((ext_vector_type(4)));

// ---------------------------------------------------------------------------
// Kernel 1 (v2): LayerNorm + dual projection + mask.  (R11-exact)
// ---------------------------------------------------------------------------
__global__ __launch_bounds__(64) void k_ln_proj(
    const float* __restrict__ s, const int* __restrict__ mask,
    const float* __restrict__ ln_scale, const float* __restrict__ ln_bias,
    const float* __restrict__ w1, const float* __restrict__ b1,
    const float* __restrict__ w2, const float* __restrict__ b2,
    float* __restrict__ a, float* __restrict__ b)
{
    __shared__ float sn_lds[CS];
    const int lane = threadIdx.x;
    const int row  = blockIdx.x;

    const float* srow = s + row * CS;
    float v[6];
    float sum = 0.f, sumsq = 0.f;
#pragma unroll
    for (int q = 0; q < 6; ++q) {
        v[q] = srow[lane + 64 * q];
        sum   += v[q];
        sumsq += v[q] * v[q];
    }
#pragma unroll
    for (int off = 32; off; off >>= 1) {
        sum   += __shfl_xor(sum, off);
        sumsq += __shfl_xor(sumsq, off);
    }
    const float mu   = sum * (1.f / CS);
    const float var  = sumsq * (1.f / CS) - mu * mu;
    const float rstd = rsqrtf(var + LN_EPS);
#pragma unroll
    for (int q = 0; q < 6; ++q) {
        const int k = lane + 64 * q;
        sn_lds[k] = (v[q] - mu) * rstd * ln_scale[k] + ln_bias[k];
    }
    __syncthreads();

    const int c    = lane & 31;
    const int half = lane >> 5;
    const float* W  = half ? w2 : w1;
    const float* Bv = half ? b2 : b1;
    float acc = 0.f;
#pragma unroll 4
    for (int k = 0; k < CS; ++k)
        acc += sn_lds[k] * W[k * CH + c];
    const float m = (float)mask[row];
    const float outv = (acc + Bv[c]) * m;
    (half ? b : a)[row * CH + c] = outv;
}

// ---------------------------------------------------------------------------
// Kernel 2: G[i][e][z] = sum_c a[i][c] * w_out[(c*CH+e)*CZ + z].  (R15-exact)
// ---------------------------------------------------------------------------
__global__ __launch_bounds__(512) void k_G(
    const float* __restrict__ a, const float* __restrict__ w_out,
    float* __restrict__ G)
{
    const int i0 = blockIdx.x * 2;
    const int t  = threadIdx.x;
    const int e  = t >> 4;             // 0..31
    const int zo = t & 15;             // z-octet: z = 8*zo .. 8*zo+7

    float a0[CH], a1[CH];
#pragma unroll
    for (int c = 0; c < CH; ++c) {
        a0[c] = a[i0 * CH + c];        // wave-uniform -> broadcast
        a1[c] = a[(i0 + 1) * CH + c];
    }

    const float* wbase = w_out + (size_t)e * CZ + 8 * zo;   // + c*CH*CZ per c
    f4 g00 = 0.f, g01 = 0.f, g10 = 0.f, g11 = 0.f;
#pragma unroll
    for (int c = 0; c < CH; ++c) {
        const f4 w0 = *(const f4*)(wbase + (size_t)c * (CH * CZ));
        const f4 w1 = *(const f4*)(wbase + (size_t)c * (CH * CZ) + 4);
        g00 += a0[c] * w0;  g01 += a0[c] * w1;
        g10 += a1[c] * w0;  g11 += a1[c] * w1;
    }

    float* Gp0 = G + (size_t)i0 * (CH * CZ) + e * CZ + 8 * zo;
    *(f4*)(Gp0)     = g00;
    *(f4*)(Gp0 + 4) = g01;
    float* Gp1 = Gp0 + CH * CZ;
    *(f4*)(Gp1)     = g10;
    *(f4*)(Gp1 + 4) = g11;
}

// ---------------------------------------------------------------------------
// Kernel 3 (v5): z[i,j,:] = sum_e b[j,e] * G[i,e,:] + b_out.
// FEED-AMORTIZED: lane holds a G f4 z-QUAD column (128 VGPR), so 32 lanes
// cover a full j-row and the wave processes a J-PAIR per step. The 8
// ds_read_b128 of b[j] now have a 2-way row split across half-waves (free
// per m136: 2-way LDS aliasing = 1.02x) and feed 2x the output — LDS-pipe
// insts per output drop 4x vs R15 (41 us -> ~20 us predicted), against a
// 13.7 us VALU floor.
// Store pattern unchanged from R15 (proven ~7 TB/s): block = one i, sweeps
// out[i] (256 KB) linearly, 8 KB per block-step, 1 KB contiguous per wave
// (j-pair adjacent). f4 stores halve store-inst count too.
// grid = 512 (block = i), block = 512 thr, ~185 VGPR -> 2 waves/SIMD.
// ---------------------------------------------------------------------------
__global__ __launch_bounds__(512, 2) void k_main(
    const float* __restrict__ b, const float* __restrict__ G,
    const float* __restrict__ b_out, float* __restrict__ out)
{
    __shared__ float b_lds[L][CH];     // 64 KB: entire b matrix

    const int i    = blockIdx.x;
    const int t    = threadIdx.x;
    const int wave = t >> 6;
    const int lane = t & 63;
    const int half = lane >> 5;        // which j of the wave's pair
    const int zq   = lane & 31;        // z-quad: z = 4*zq

    // Stage all of b: 16384 floats = 512 threads x 8 float4.
#pragma unroll
    for (int k = 0; k < 8; ++k)
        ((f4*)b_lds)[t + k * 512] = ((const f4*)b)[t + k * 512];

    // G[i] z-quad column for this lane: 128 VGPRs (f4-coalesced, L2/L3-hot).
    f4 G_reg[CH];
    const float* Gi = G + (size_t)i * (CH * CZ) + 4 * zq;
#pragma unroll
    for (int e = 0; e < CH; ++e)
        G_reg[e] = *(const f4*)(Gi + e * CZ);

    const f4 bo = ((const f4*)b_out)[zq];
    float* op = out + (size_t)i * (L * CZ);

    __syncthreads();

#pragma unroll 2
    for (int s = 0; s < 32; ++s) {
        const int j = s * 16 + 2 * wave + half;
        const f4* bp = (const f4*)&b_lds[j][0];   // 2-way row split (free)
        f4 acc = bo;
#pragma unroll
        for (int q = 0; q < 8; ++q) {
            const f4 r = bp[q];
            acc += r.x * G_reg[4 * q + 0];
            acc += r.y * G_reg[4 * q + 1];
            acc += r.z * G_reg[4 * q + 2];
            acc += r.w * G_reg[4 * q + 3];
        }
        // 1 KB contiguous per wave (j-pair rows adjacent); 8 KB per block-step.
        *(f4*)(op + (size_t)j * CZ + 4 * zq) = acc;
    }
}

// ---------------------------------------------------------------------------
extern "C" void kernel_launch(void* const* d_in, const int* in_sizes, int n_in,
                              void* d_out, int out_size, void* d_ws, size_t ws_size,
                              hipStream_t stream) {
    const float* s        = (const float*)d_in[0];
    const int*   mask     = (const int*)d_in[1];
    const float* ln_scale = (const float*)d_in[2];
    const float* ln_bias  = (const float*)d_in[3];
    const float* w1       = (const float*)d_in[4];
    const float* b1       = (const float*)d_in[5];
    const float* w2       = (const float*)d_in[6];
    const float* b2       = (const float*)d_in[7];
    const float* w_out    = (const float*)d_in[8];
    const float* b_out    = (const float*)d_in[9];
    float* out = (float*)d_out;

    // Workspace: a [512*32], b [512*32], G [512*32*128]  (8.125 MB total).
    float* a = (float*)d_ws;
    float* b = a + L * CH;
    float* G = b + L * CH;

    k_ln_proj<<<L, 64, 0, stream>>>(s, mask, ln_scale, ln_bias,
                                    w1, b1, w2, b2, a, b);
    k_G<<<L / 2, 512, 0, stream>>>(a, w_out, G);
    k_main<<<L, 512, 0, stream>>>(b, G, b_out, out);
}